// Round 2
// baseline (1425.649 us; speedup 1.0000x reference)
//
#include <hip/hip_runtime.h>
#include <hip/hip_bf16.h>
#include <math.h>

#define PI_F 3.14159265358979323846f

static constexpr int F = 128;
static constexpr int KB = 30;     // sinc basis size
static constexpr int LAYERS = 3;
static constexpr float CUT = 4.0f;
static constexpr int GEOMW = 34;  // unit(3) + cc(1) + state(30)

// ---------------- CSR build ----------------
__global__ void k_count(const int* __restrict__ edges, int* __restrict__ cnt, int E) {
    int i = blockIdx.x * blockDim.x + threadIdx.x;
    if (i < E) atomicAdd(&cnt[edges[2 * i + 1]], 1);
}

__global__ void k_scan(const int* __restrict__ cnt, int* __restrict__ off, int n) {
    __shared__ int part[1024];
    int t = threadIdx.x;
    int chunk = (n + 1023) / 1024;
    int b = t * chunk; if (b > n) b = n;
    int e = b + chunk; if (e > n) e = n;
    int s = 0;
    for (int i = b; i < e; i++) s += cnt[i];
    part[t] = s;
    __syncthreads();
    for (int o = 1; o < 1024; o <<= 1) {
        int v = part[t];
        int add = (t >= o) ? part[t - o] : 0;
        __syncthreads();
        part[t] = v + add;
        __syncthreads();
    }
    int run = (t == 0) ? 0 : part[t - 1];
    for (int i = b; i < e; i++) { off[i] = run; run += cnt[i]; }
    if (t == 1023) off[n] = part[1023];
}

__global__ void k_scatter(const int* __restrict__ edges, int* __restrict__ cur,
                          int* __restrict__ eids, int E) {
    int i = blockIdx.x * blockDim.x + threadIdx.x;
    if (i < E) {
        int d = edges[2 * i + 1];
        int pos = atomicAdd(&cur[d], 1);
        eids[pos] = i;
    }
}

// ---------------- geometry precompute ----------------
__global__ void k_geom(const float* __restrict__ src_xyz, const float* __restrict__ dst_xyz,
                       const float* __restrict__ disp, const float* __restrict__ cell,
                       const int* __restrict__ edges, float* __restrict__ geom, int E) {
    int e = blockIdx.x * blockDim.x + threadIdx.x;
    if (e >= E) return;
    int s = edges[2 * e], d = edges[2 * e + 1];
    const float* dp = disp + 3 * (size_t)e;
    float dx[3];
#pragma unroll
    for (int i = 0; i < 3; i++) {
        float dc = dp[0] * cell[0 * 3 + i] + dp[1] * cell[1 * 3 + i] + dp[2] * cell[2 * 3 + i];
        dx[i] = dst_xyz[3 * d + i] - (src_xyz[3 * s + i] + dc);
    }
    float dist = sqrtf(dx[0] * dx[0] + dx[1] * dx[1] + dx[2] * dx[2]);
    float inv = 1.0f / fmaxf(dist, 1e-12f);
    float* g = geom + (size_t)e * GEOMW;
    g[0] = dx[0] * inv; g[1] = dx[1] * inv; g[2] = dx[2] * inv;
    g[3] = (dist < CUT) ? 0.5f * (cosf(PI_F * dist / CUT) + 1.0f) : 0.0f;
#pragma unroll
    for (int k = 0; k < KB; k++) {
        float kk = (float)(k + 1);
        g[4 + k] = (dist > 1e-12f) ? sinf(PI_F * dist * kk / CUT) / dist : PI_F * kk / CUT;
    }
}

// ---------------- init: s0 = embed[Z] ----------------
__global__ void k_embed(const int* __restrict__ Z, const float* __restrict__ emb,
                        float* __restrict__ s, int n) {
    int i = blockIdx.x * blockDim.x + threadIdx.x;
    if (i < n * F) s[i] = emb[(size_t)Z[i / F] * F + (i % F)];
}

// ---------------- generic f32 GEMM: C = act(A@B + bias) ----------------
// A (M,K) rm, B (K,N) rm, C (M,N) rm. N % 64 == 0, K % 16 == 0.
// act: 0 none, 1 silu, 2 sigmoid.  outmode: 0 -> f32 C, 1 -> bf16 C.
__global__ __launch_bounds__(256) void k_gemm(const float* __restrict__ A, const float* __restrict__ B,
                                              const float* __restrict__ bias, void* __restrict__ Cout,
                                              int M, int N, int K, int act, int outmode) {
    __shared__ float As[16][64];
    __shared__ float Bs[16][64];
    int tid = threadIdx.x;
    int bm = blockIdx.y * 64, bn = blockIdx.x * 64;
    int tx = tid & 15, ty = tid >> 4;
    float acc[4][4] = {};
    int arow = tid >> 2;
    int acol = (tid & 3) * 4;
    int brow = tid >> 4;
    int bcol = (tid & 15) * 4;
    for (int k0 = 0; k0 < K; k0 += 16) {
        float4 av = make_float4(0.f, 0.f, 0.f, 0.f);
        int gm = bm + arow;
        if (gm < M) av = *reinterpret_cast<const float4*>(A + (size_t)gm * K + k0 + acol);
        As[acol + 0][arow] = av.x; As[acol + 1][arow] = av.y;
        As[acol + 2][arow] = av.z; As[acol + 3][arow] = av.w;
        float4 bv = *reinterpret_cast<const float4*>(B + (size_t)(k0 + brow) * N + bn + bcol);
        Bs[brow][bcol + 0] = bv.x; Bs[brow][bcol + 1] = bv.y;
        Bs[brow][bcol + 2] = bv.z; Bs[brow][bcol + 3] = bv.w;
        __syncthreads();
#pragma unroll
        for (int k = 0; k < 16; k++) {
            float a0 = As[k][ty * 4 + 0], a1 = As[k][ty * 4 + 1];
            float a2 = As[k][ty * 4 + 2], a3 = As[k][ty * 4 + 3];
            float b0 = Bs[k][tx * 4 + 0], b1 = Bs[k][tx * 4 + 1];
            float b2 = Bs[k][tx * 4 + 2], b3 = Bs[k][tx * 4 + 3];
            acc[0][0] += a0 * b0; acc[0][1] += a0 * b1; acc[0][2] += a0 * b2; acc[0][3] += a0 * b3;
            acc[1][0] += a1 * b0; acc[1][1] += a1 * b1; acc[1][2] += a1 * b2; acc[1][3] += a1 * b3;
            acc[2][0] += a2 * b0; acc[2][1] += a2 * b1; acc[2][2] += a2 * b2; acc[2][3] += a2 * b3;
            acc[3][0] += a3 * b0; acc[3][1] += a3 * b1; acc[3][2] += a3 * b2; acc[3][3] += a3 * b3;
        }
        __syncthreads();
    }
#pragma unroll
    for (int i = 0; i < 4; i++) {
        int gm = bm + ty * 4 + i;
        if (gm >= M) continue;
#pragma unroll
        for (int j = 0; j < 4; j++) {
            int gn = bn + tx * 4 + j;
            float v = acc[i][j];
            if (bias) v += bias[gn];
            if (act == 1) v = v / (1.0f + expf(-v));
            else if (act == 2) v = 1.0f / (1.0f + expf(-v));
            if (outmode == 0) ((float*)Cout)[(size_t)gm * N + gn] = v;
            else ((__hip_bfloat16*)Cout)[(size_t)gm * N + gn] = __float2bfloat16(v);
        }
    }
}

// ---------------- fused edge messages + segment sum (dst-centric) ----------------
// phi/vsend are bf16 (gathered operands); residual s_in/v_in stay f32.
__global__ __launch_bounds__(128) void k_gather(
    const float* __restrict__ geom, const int* __restrict__ eoff, const int* __restrict__ eids,
    const int* __restrict__ edges, const __hip_bfloat16* __restrict__ phi,
    const __hip_bfloat16* __restrict__ vsend,
    const float* __restrict__ fw, const float* __restrict__ fb,
    const float* __restrict__ s_in, const float* __restrict__ v_in,
    float* __restrict__ s_out, float* __restrict__ v_out, int ndst) {
    const int t = threadIdx.x;  // 0..127, owns cols t, t+128, t+256
    float fw0[KB], fw1[KB], fw2[KB];
#pragma unroll
    for (int k = 0; k < KB; k++) {
        fw0[k] = fw[k * 384 + t];
        fw1[k] = fw[k * 384 + 128 + t];
        fw2[k] = fw[k * 384 + 256 + t];
    }
    const float fb0 = fb[t], fb1 = fb[128 + t], fb2 = fb[256 + t];
    for (int d = blockIdx.x; d < ndst; d += gridDim.x) {
        const int e0 = eoff[d], e1 = eoff[d + 1];
        float accs = 0.f, av0 = 0.f, av1 = 0.f, av2 = 0.f;
        for (int ii = e0; ii < e1; ii++) {
            const int e = eids[ii];
            const int src = edges[2 * e];
            const float* g = geom + (size_t)e * GEOMW;
            const float u0 = g[0], u1 = g[1], u2 = g[2], cc = g[3];
            float f0 = 0.f, f1 = 0.f, f2 = 0.f;
#pragma unroll
            for (int k = 0; k < KB; k++) {
                const float st = g[4 + k];
                f0 += st * fw0[k]; f1 += st * fw1[k]; f2 += st * fw2[k];
            }
            f0 = (f0 + fb0) * cc; f1 = (f1 + fb1) * cc; f2 = (f2 + fb2) * cc;
            const __hip_bfloat16* ph = phi + (size_t)src * 384;
            const float gsv = f0 * __bfloat162float(ph[t]);
            const float gev = f1 * __bfloat162float(ph[128 + t]);
            const float gss = f2 * __bfloat162float(ph[256 + t]);
            const __hip_bfloat16* vs = vsend + (size_t)src * 384;
            accs += gss;
            av0 += __bfloat162float(vs[t]) * gsv + gev * u0;
            av1 += __bfloat162float(vs[128 + t]) * gsv + gev * u1;
            av2 += __bfloat162float(vs[256 + t]) * gsv + gev * u2;
        }
        if (s_in) {
            accs += s_in[(size_t)d * 128 + t];
            av0 += v_in[(size_t)d * 384 + t];
            av1 += v_in[(size_t)d * 384 + 128 + t];
            av2 += v_in[(size_t)d * 384 + 256 + t];
        }
        s_out[(size_t)d * 128 + t] = accs;
        v_out[(size_t)d * 384 + t] = av0;
        v_out[(size_t)d * 384 + 128 + t] = av1;
        v_out[(size_t)d * 384 + 256 + t] = av2;
    }
}

// ---------------- cat = [s, ||Vv||_axis1] ----------------
__global__ void k_catnorm(const float* __restrict__ s, const float* __restrict__ Vv,
                          float* __restrict__ cat, int n) {
    int i = blockIdx.x * blockDim.x + threadIdx.x;
    if (i >= n * F) return;
    int nn = i / F, g = i % F;
    size_t b = (size_t)nn * 384;
    float w0 = Vv[b + g], w1 = Vv[b + 128 + g], w2 = Vv[b + 256 + g];
    cat[(size_t)nn * 256 + g] = s[i];
    cat[(size_t)nn * 256 + 128 + g] = sqrtf(w0 * w0 + w1 * w1 + w2 * w2);
}

// ---------------- painn update (optionally also emit bf16 copy of v_out) ----------------
__global__ void k_update(const float* __restrict__ s_in, const float* __restrict__ v_in,
                         const float* __restrict__ a, const float* __restrict__ Uv,
                         const float* __restrict__ Vv,
                         float* __restrict__ s_out, float* __restrict__ v_out,
                         __hip_bfloat16* __restrict__ v_out_bf, int n) {
    int i = blockIdx.x * blockDim.x + threadIdx.x;
    if (i >= n * F) return;
    int nn = i / F, g = i % F;
    size_t b = (size_t)nn * 384;
    float u0 = Uv[b + g], u1 = Uv[b + 128 + g], u2 = Uv[b + 256 + g];
    float w0 = Vv[b + g], w1 = Vv[b + 128 + g], w2 = Vv[b + 256 + g];
    float inner = u0 * w0 + u1 * w1 + u2 * w2;
    float ass = a[b + g], asv = a[b + 128 + g], avv = a[b + 256 + g];
    s_out[i] = s_in[i] + ass + asv * inner;
    float r0 = v_in[b + g] + avv * u0;
    float r1 = v_in[b + 128 + g] + avv * u1;
    float r2 = v_in[b + 256 + g] + avv * u2;
    v_out[b + g] = r0;
    v_out[b + 128 + g] = r1;
    v_out[b + 256 + g] = r2;
    if (v_out_bf) {
        v_out_bf[b + g] = __float2bfloat16(r0);
        v_out_bf[b + 128 + g] = __float2bfloat16(r1);
        v_out_bf[b + 256 + g] = __float2bfloat16(r2);
    }
}

// ---------------- gated blend ----------------
__global__ void k_blend(const float* __restrict__ gate, const float* __restrict__ ms,
                        const float* __restrict__ mv, float* __restrict__ ps,
                        float* __restrict__ pv, int n) {
    int i = blockIdx.x * blockDim.x + threadIdx.x;
    if (i >= n * F) return;
    int p = i / F, g = i % F;
    float gs = gate[(size_t)p * 256 + g];
    float gv = gate[(size_t)p * 256 + 128 + g];
    ps[i] = ps[i] * gs + (1.0f - gs) * ms[i];
    size_t b = (size_t)p * 384;
#pragma unroll
    for (int i3 = 0; i3 < 3; i3++) {
        size_t o = b + (size_t)i3 * 128 + g;
        pv[o] = pv[o] * gv + (1.0f - gv) * mv[o];
    }
}

extern "C" void kernel_launch(void* const* d_in, const int* in_sizes, int n_in,
                              void* d_out, int out_size, void* d_ws, size_t ws_size,
                              hipStream_t stream) {
    const float* atom_xyz  = (const float*)d_in[0];
    const float* probe_xyz = (const float*)d_in[1];
    const float* cell      = (const float*)d_in[2];
    const float* a_disp    = (const float*)d_in[3];
    const float* p_disp    = (const float*)d_in[4];
    const float* atom_embed= (const float*)d_in[5];
    const float* ai_fw = (const float*)d_in[6];
    const float* ai_fb = (const float*)d_in[7];
    const float* ai_w1 = (const float*)d_in[8];
    const float* ai_b1 = (const float*)d_in[9];
    const float* ai_w2 = (const float*)d_in[10];
    const float* ai_b2 = (const float*)d_in[11];
    const float* au_U  = (const float*)d_in[12];
    const float* au_V  = (const float*)d_in[13];
    const float* au_w1 = (const float*)d_in[14];
    const float* au_b1 = (const float*)d_in[15];
    const float* au_w2 = (const float*)d_in[16];
    const float* au_b2 = (const float*)d_in[17];
    const float* pm_fw = (const float*)d_in[18];
    const float* pm_fb = (const float*)d_in[19];
    const float* pm_w1 = (const float*)d_in[20];
    const float* pm_b1 = (const float*)d_in[21];
    const float* pm_w2 = (const float*)d_in[22];
    const float* pm_b2 = (const float*)d_in[23];
    const float* pm_gw1= (const float*)d_in[24];
    const float* pm_gb1= (const float*)d_in[25];
    const float* pm_gw2= (const float*)d_in[26];
    const float* pm_gb2= (const float*)d_in[27];
    const float* pu_U  = (const float*)d_in[28];
    const float* pu_V  = (const float*)d_in[29];
    const float* pu_w1 = (const float*)d_in[30];
    const float* pu_b1 = (const float*)d_in[31];
    const float* pu_w2 = (const float*)d_in[32];
    const float* pu_b2 = (const float*)d_in[33];
    const int* nodes_Z = (const int*)d_in[34];
    const int* a_edges = (const int*)d_in[35];
    const int* p_edges = (const int*)d_in[36];

    const int N  = in_sizes[34];
    const int EA = in_sizes[35] / 2;
    const int EP = in_sizes[36] / 2;
    const int P  = in_sizes[1] / 3;

    char* w = (char*)d_ws;
    size_t off = 0;
    auto alloc = [&](size_t bytes) -> void* {
        void* p = w + off;
        off = (off + bytes + 255) & ~(size_t)255;
        return p;
    };
    int* a_off  = (int*)alloc((size_t)(N + 1) * 4);
    int* a_cur  = (int*)alloc((size_t)N * 4);
    int* a_eids = (int*)alloc((size_t)EA * 4);
    int* p_off  = (int*)alloc((size_t)(P + 1) * 4);
    int* p_cur  = (int*)alloc((size_t)P * 4);
    int* p_eids = (int*)alloc((size_t)EP * 4);
    float* a_geom = (float*)alloc((size_t)EA * GEOMW * 4);
    float* p_geom = (float*)alloc((size_t)EP * GEOMW * 4);
    float* s0     = (float*)alloc((size_t)N * F * 4);
    float* v0     = (float*)alloc((size_t)N * 3 * F * 4);
    float* s_list = (float*)alloc((size_t)LAYERS * N * F * 4);
    float* v_list = (float*)alloc((size_t)LAYERS * N * 3 * F * 4);
    float* ms     = (float*)alloc((size_t)P * F * 4);       // msg s / atom s_tmp
    float* mv     = (float*)alloc((size_t)P * 3 * F * 4);   // msg v / atom v_tmp
    float* hbuf   = (float*)alloc((size_t)P * 2 * F * 4);
    float* Uv     = (float*)alloc((size_t)P * 3 * F * 4);
    float* Vv     = (float*)alloc((size_t)P * 3 * F * 4);
    float* cat    = (float*)alloc((size_t)P * 2 * F * 4);
    float* abuf   = (float*)alloc((size_t)P * 3 * F * 4);
    float* gatebuf= (float*)alloc((size_t)P * 2 * F * 4);
    __hip_bfloat16* phi_bf   = (__hip_bfloat16*)alloc((size_t)N * 3 * F * 2);
    __hip_bfloat16* v0_bf    = (__hip_bfloat16*)alloc((size_t)N * 3 * F * 2);
    __hip_bfloat16* v_list_bf= (__hip_bfloat16*)alloc((size_t)LAYERS * N * 3 * F * 2);
    (void)ws_size; (void)n_in;

    // CSR atoms
    hipMemsetAsync(a_cur, 0, (size_t)N * 4, stream);
    k_count<<<(EA + 255) / 256, 256, 0, stream>>>(a_edges, a_cur, EA);
    k_scan<<<1, 1024, 0, stream>>>(a_cur, a_off, N);
    hipMemcpyAsync(a_cur, a_off, (size_t)N * 4, hipMemcpyDeviceToDevice, stream);
    k_scatter<<<(EA + 255) / 256, 256, 0, stream>>>(a_edges, a_cur, a_eids, EA);
    // CSR probes
    hipMemsetAsync(p_cur, 0, (size_t)P * 4, stream);
    k_count<<<(EP + 255) / 256, 256, 0, stream>>>(p_edges, p_cur, EP);
    k_scan<<<1, 1024, 0, stream>>>(p_cur, p_off, P);
    hipMemcpyAsync(p_cur, p_off, (size_t)P * 4, hipMemcpyDeviceToDevice, stream);
    k_scatter<<<(EP + 255) / 256, 256, 0, stream>>>(p_edges, p_cur, p_eids, EP);

    // geometry
    k_geom<<<(EA + 255) / 256, 256, 0, stream>>>(atom_xyz, atom_xyz, a_disp, cell, a_edges, a_geom, EA);
    k_geom<<<(EP + 255) / 256, 256, 0, stream>>>(atom_xyz, probe_xyz, p_disp, cell, p_edges, p_geom, EP);

    // init node states
    k_embed<<<(N * F + 255) / 256, 256, 0, stream>>>(nodes_Z, atom_embed, s0, N);
    hipMemsetAsync(v0, 0, (size_t)N * 3 * F * 4, stream);
    hipMemsetAsync(v0_bf, 0, (size_t)N * 3 * F * 2, stream);

    auto gemm = [&](const float* A, const float* B, const float* bias, void* C,
                    int M, int Nc, int K, int act, int outmode = 0) {
        dim3 g(Nc / 64, (M + 63) / 64);
        k_gemm<<<g, 256, 0, stream>>>(A, B, bias, C, M, Nc, K, act, outmode);
    };

    // ---- atom message-passing layers ----
    for (int l = 0; l < LAYERS; l++) {
        const float* scur = l ? (s_list + (size_t)(l - 1) * N * F) : s0;
        const float* vcur = l ? (v_list + (size_t)(l - 1) * N * 3 * F) : v0;
        const __hip_bfloat16* vcur_bf = l ? (v_list_bf + (size_t)(l - 1) * N * 3 * F) : v0_bf;
        gemm(scur, ai_w1 + (size_t)l * F * F, ai_b1 + (size_t)l * F, hbuf, N, F, F, 1);
        gemm(hbuf, ai_w2 + (size_t)l * F * 3 * F, ai_b2 + (size_t)l * 3 * F, phi_bf, N, 3 * F, F, 0, 1);
        k_gather<<<N, 128, 0, stream>>>(a_geom, a_off, a_eids, a_edges, phi_bf, vcur_bf,
                                        ai_fw + (size_t)l * KB * 3 * F, ai_fb + (size_t)l * 3 * F,
                                        scur, vcur, ms, mv, N);
        gemm(mv, au_U + (size_t)l * F * F, nullptr, Uv, 3 * N, F, F, 0);
        gemm(mv, au_V + (size_t)l * F * F, nullptr, Vv, 3 * N, F, F, 0);
        k_catnorm<<<(N * F + 255) / 256, 256, 0, stream>>>(ms, Vv, cat, N);
        gemm(cat, au_w1 + (size_t)l * 2 * F * F, au_b1 + (size_t)l * F, hbuf, N, F, 2 * F, 1);
        gemm(hbuf, au_w2 + (size_t)l * F * 3 * F, au_b2 + (size_t)l * 3 * F, abuf, N, 3 * F, F, 0);
        k_update<<<(N * F + 255) / 256, 256, 0, stream>>>(ms, mv, abuf, Uv, Vv,
                  s_list + (size_t)l * N * F, v_list + (size_t)l * N * 3 * F,
                  v_list_bf + (size_t)l * N * 3 * F, N);
    }

    // ---- probe phase ----
    float* ps = (float*)d_out;
    float* pv = (float*)d_out + (size_t)P * F;
    hipMemsetAsync(d_out, 0, (size_t)out_size * 4, stream);

    for (int l = 0; l < LAYERS; l++) {
        const float* sl = s_list + (size_t)l * N * F;
        const __hip_bfloat16* vl_bf = v_list_bf + (size_t)l * N * 3 * F;
        gemm(sl, pm_w1 + (size_t)l * F * F, pm_b1 + (size_t)l * F, hbuf, N, F, F, 1);
        gemm(hbuf, pm_w2 + (size_t)l * F * 3 * F, pm_b2 + (size_t)l * 3 * F, phi_bf, N, 3 * F, F, 0, 1);
        k_gather<<<P, 128, 0, stream>>>(p_geom, p_off, p_eids, p_edges, phi_bf, vl_bf,
                                        pm_fw + (size_t)l * KB * 3 * F, pm_fb + (size_t)l * 3 * F,
                                        nullptr, nullptr, ms, mv, P);
        gemm(ms, pm_gw1 + (size_t)l * F * 2 * F, pm_gb1 + (size_t)l * 2 * F, hbuf, P, 2 * F, F, 1);
        gemm(hbuf, pm_gw2 + (size_t)l * 2 * F * 2 * F, pm_gb2 + (size_t)l * 2 * F, gatebuf, P, 2 * F, 2 * F, 2);
        k_blend<<<(P * F + 255) / 256, 256, 0, stream>>>(gatebuf, ms, mv, ps, pv, P);
        gemm(pv, pu_U + (size_t)l * F * F, nullptr, Uv, 3 * P, F, F, 0);
        gemm(pv, pu_V + (size_t)l * F * F, nullptr, Vv, 3 * P, F, F, 0);
        k_catnorm<<<(P * F + 255) / 256, 256, 0, stream>>>(ps, Vv, cat, P);
        gemm(cat, pu_w1 + (size_t)l * 2 * F * F, pu_b1 + (size_t)l * F, hbuf, P, F, 2 * F, 1);
        gemm(hbuf, pu_w2 + (size_t)l * F * 3 * F, pu_b2 + (size_t)l * 3 * F, abuf, P, 3 * F, F, 0);
        k_update<<<(P * F + 255) / 256, 256, 0, stream>>>(ps, pv, abuf, Uv, Vv, ps, pv, nullptr, P);
    }
}

// Round 3
// 1388.643 us; speedup vs baseline: 1.0266x; 1.0266x over previous
//
#include <hip/hip_runtime.h>
#include <hip/hip_bf16.h>
#include <math.h>

#define PI_F 3.14159265358979323846f

static constexpr int F = 128;
static constexpr int KB = 30;     // sinc basis size
static constexpr int LAYERS = 3;
static constexpr float CUT = 4.0f;

// geom layout per edge (CSR-ordered): 9 float4 = [u0,u1,u2,cc][st0..3]...[st28,st29,0,0]
// st[k] has cc pre-folded in.

__device__ __forceinline__ float edge_dist(const float* __restrict__ sxyz,
                                           const float* __restrict__ dxyz,
                                           const float* __restrict__ disp,
                                           const float* __restrict__ cell,
                                           int s, int d, int e, float* dx) {
    const float* dp = disp + 3 * (size_t)e;
#pragma unroll
    for (int i = 0; i < 3; i++) {
        float dc = dp[0] * cell[0 * 3 + i] + dp[1] * cell[1 * 3 + i] + dp[2] * cell[2 * 3 + i];
        dx[i] = dxyz[3 * d + i] - (sxyz[3 * s + i] + dc);
    }
    return sqrtf(dx[0] * dx[0] + dx[1] * dx[1] + dx[2] * dx[2]);
}

// ---------------- CSR build (cutoff-filtered) ----------------
__global__ void k_count(const int* __restrict__ edges, const float* __restrict__ sxyz,
                        const float* __restrict__ dxyz, const float* __restrict__ disp,
                        const float* __restrict__ cell, int* __restrict__ cnt, int E) {
    int i = blockIdx.x * blockDim.x + threadIdx.x;
    if (i >= E) return;
    int s = edges[2 * i], d = edges[2 * i + 1];
    float dx[3];
    float dist = edge_dist(sxyz, dxyz, disp, cell, s, d, i, dx);
    if (dist < CUT) atomicAdd(&cnt[d], 1);
}

__global__ void k_scan(const int* __restrict__ cnt, int* __restrict__ off, int n) {
    __shared__ int part[1024];
    int t = threadIdx.x;
    int chunk = (n + 1023) / 1024;
    int b = t * chunk; if (b > n) b = n;
    int e = b + chunk; if (e > n) e = n;
    int s = 0;
    for (int i = b; i < e; i++) s += cnt[i];
    part[t] = s;
    __syncthreads();
    for (int o = 1; o < 1024; o <<= 1) {
        int v = part[t];
        int add = (t >= o) ? part[t - o] : 0;
        __syncthreads();
        part[t] = v + add;
        __syncthreads();
    }
    int run = (t == 0) ? 0 : part[t - 1];
    for (int i = b; i < e; i++) { off[i] = run; run += cnt[i]; }
    if (t == 1023) off[n] = part[1023];
}

__global__ void k_scatter(const int* __restrict__ edges, const float* __restrict__ sxyz,
                          const float* __restrict__ dxyz, const float* __restrict__ disp,
                          const float* __restrict__ cell, int* __restrict__ cur,
                          int* __restrict__ eids, int E) {
    int i = blockIdx.x * blockDim.x + threadIdx.x;
    if (i >= E) return;
    int s = edges[2 * i], d = edges[2 * i + 1];
    float dx[3];
    float dist = edge_dist(sxyz, dxyz, disp, cell, s, d, i, dx);
    if (dist < CUT) {
        int pos = atomicAdd(&cur[d], 1);
        eids[pos] = i;
    }
}

// ---------------- geometry precompute, CSR-ordered, cc folded into state ----------------
__global__ void k_geom(const float* __restrict__ sxyz, const float* __restrict__ dxyz,
                       const float* __restrict__ disp, const float* __restrict__ cell,
                       const int* __restrict__ edges, const int* __restrict__ eids,
                       const int* __restrict__ eoff, int ndst,
                       float4* __restrict__ geomv, int* __restrict__ srcs) {
    int pos = blockIdx.x * blockDim.x + threadIdx.x;
    if (pos >= eoff[ndst]) return;
    int e = eids[pos];
    int s = edges[2 * e], d = edges[2 * e + 1];
    float dx[3];
    float dist = edge_dist(sxyz, dxyz, disp, cell, s, d, e, dx);
    float inv = 1.0f / fmaxf(dist, 1e-12f);
    float cc = (dist < CUT) ? 0.5f * (cosf(PI_F * dist / CUT) + 1.0f) : 0.0f;
    float st[32];
#pragma unroll
    for (int k = 0; k < KB; k++) {
        float kk = (float)(k + 1);
        st[k] = cc * ((dist > 1e-12f) ? sinf(PI_F * dist * kk / CUT) / dist : PI_F * kk / CUT);
    }
    st[30] = 0.f; st[31] = 0.f;
    float4* g = geomv + (size_t)pos * 9;
    g[0] = make_float4(dx[0] * inv, dx[1] * inv, dx[2] * inv, cc);
#pragma unroll
    for (int c = 0; c < 8; c++)
        g[1 + c] = make_float4(st[c * 4], st[c * 4 + 1], st[c * 4 + 2], st[c * 4 + 3]);
    srcs[pos] = s;
}

// ---------------- init: s0 = embed[Z] ----------------
__global__ void k_embed(const int* __restrict__ Z, const float* __restrict__ emb,
                        float* __restrict__ s, int n) {
    int i = blockIdx.x * blockDim.x + threadIdx.x;
    if (i < n * F) s[i] = emb[(size_t)Z[i / F] * F + (i % F)];
}

// ---------------- generic f32 GEMM: C = act(A@B + bias) ----------------
__global__ __launch_bounds__(256) void k_gemm(const float* __restrict__ A, const float* __restrict__ B,
                                              const float* __restrict__ bias, void* __restrict__ Cout,
                                              int M, int N, int K, int act, int outmode) {
    __shared__ float As[16][64];
    __shared__ float Bs[16][64];
    int tid = threadIdx.x;
    int bm = blockIdx.y * 64, bn = blockIdx.x * 64;
    int tx = tid & 15, ty = tid >> 4;
    float acc[4][4] = {};
    int arow = tid >> 2;
    int acol = (tid & 3) * 4;
    int brow = tid >> 4;
    int bcol = (tid & 15) * 4;
    for (int k0 = 0; k0 < K; k0 += 16) {
        float4 av = make_float4(0.f, 0.f, 0.f, 0.f);
        int gm = bm + arow;
        if (gm < M) av = *reinterpret_cast<const float4*>(A + (size_t)gm * K + k0 + acol);
        As[acol + 0][arow] = av.x; As[acol + 1][arow] = av.y;
        As[acol + 2][arow] = av.z; As[acol + 3][arow] = av.w;
        float4 bv = *reinterpret_cast<const float4*>(B + (size_t)(k0 + brow) * N + bn + bcol);
        Bs[brow][bcol + 0] = bv.x; Bs[brow][bcol + 1] = bv.y;
        Bs[brow][bcol + 2] = bv.z; Bs[brow][bcol + 3] = bv.w;
        __syncthreads();
#pragma unroll
        for (int k = 0; k < 16; k++) {
            float a0 = As[k][ty * 4 + 0], a1 = As[k][ty * 4 + 1];
            float a2 = As[k][ty * 4 + 2], a3 = As[k][ty * 4 + 3];
            float b0 = Bs[k][tx * 4 + 0], b1 = Bs[k][tx * 4 + 1];
            float b2 = Bs[k][tx * 4 + 2], b3 = Bs[k][tx * 4 + 3];
            acc[0][0] += a0 * b0; acc[0][1] += a0 * b1; acc[0][2] += a0 * b2; acc[0][3] += a0 * b3;
            acc[1][0] += a1 * b0; acc[1][1] += a1 * b1; acc[1][2] += a1 * b2; acc[1][3] += a1 * b3;
            acc[2][0] += a2 * b0; acc[2][1] += a2 * b1; acc[2][2] += a2 * b2; acc[2][3] += a2 * b3;
            acc[3][0] += a3 * b0; acc[3][1] += a3 * b1; acc[3][2] += a3 * b2; acc[3][3] += a3 * b3;
        }
        __syncthreads();
    }
#pragma unroll
    for (int i = 0; i < 4; i++) {
        int gm = bm + ty * 4 + i;
        if (gm >= M) continue;
#pragma unroll
        for (int j = 0; j < 4; j++) {
            int gn = bn + tx * 4 + j;
            float v = acc[i][j];
            if (bias) v += bias[gn];
            if (act == 1) v = v / (1.0f + expf(-v));
            else if (act == 2) v = 1.0f / (1.0f + expf(-v));
            if (outmode == 0) ((float*)Cout)[(size_t)gm * N + gn] = v;
            else ((__hip_bfloat16*)Cout)[(size_t)gm * N + gn] = __float2bfloat16(v);
        }
    }
}

// ---------------- fused edge messages + segment sum (dst-centric, CSR-streamed) ----------------
__global__ __launch_bounds__(256) void k_gather(
    const float4* __restrict__ geomv, const int* __restrict__ srcs,
    const int* __restrict__ eoff,
    const __hip_bfloat16* __restrict__ phi, const __hip_bfloat16* __restrict__ vsend,
    const float* __restrict__ fw, const float* __restrict__ fb,
    const float* __restrict__ s_in, const float* __restrict__ v_in,
    float* __restrict__ s_out, float* __restrict__ v_out, int ndst) {
    const int t = threadIdx.x & 127;     // column owner: t, t+128, t+256
    const int half = threadIdx.x >> 7;   // 2 destinations per block
    float fw0[32], fw1[32], fw2[32];
#pragma unroll
    for (int k = 0; k < 32; k++) {
        fw0[k] = (k < KB) ? fw[k * 384 + t] : 0.f;
        fw1[k] = (k < KB) ? fw[k * 384 + 128 + t] : 0.f;
        fw2[k] = (k < KB) ? fw[k * 384 + 256 + t] : 0.f;
    }
    const float fb0 = fb[t], fb1 = fb[128 + t], fb2 = fb[256 + t];
    for (int d = blockIdx.x * 2 + half; d < ndst; d += gridDim.x * 2) {
        const int e0 = eoff[d], e1 = eoff[d + 1];
        float accs = 0.f, av0 = 0.f, av1 = 0.f, av2 = 0.f;
        for (int ii = e0; ii < e1; ++ii) {
            const int src = srcs[ii];
            const float4* __restrict__ g = geomv + (size_t)ii * 9;
            const __hip_bfloat16* __restrict__ ph = phi + (size_t)src * 384;
            const __hip_bfloat16* __restrict__ vs = vsend + (size_t)src * 384;
            const float p0 = __bfloat162float(ph[t]);
            const float p1 = __bfloat162float(ph[128 + t]);
            const float p2 = __bfloat162float(ph[256 + t]);
            const float w0 = __bfloat162float(vs[t]);
            const float w1 = __bfloat162float(vs[128 + t]);
            const float w2 = __bfloat162float(vs[256 + t]);
            const float4 u = g[0];
            float f0 = fb0 * u.w, f1 = fb1 * u.w, f2 = fb2 * u.w;
#pragma unroll
            for (int c = 0; c < 8; ++c) {
                const float4 sv = g[1 + c];
                f0 = fmaf(sv.x, fw0[c * 4 + 0], f0);
                f1 = fmaf(sv.x, fw1[c * 4 + 0], f1);
                f2 = fmaf(sv.x, fw2[c * 4 + 0], f2);
                f0 = fmaf(sv.y, fw0[c * 4 + 1], f0);
                f1 = fmaf(sv.y, fw1[c * 4 + 1], f1);
                f2 = fmaf(sv.y, fw2[c * 4 + 1], f2);
                f0 = fmaf(sv.z, fw0[c * 4 + 2], f0);
                f1 = fmaf(sv.z, fw1[c * 4 + 2], f1);
                f2 = fmaf(sv.z, fw2[c * 4 + 2], f2);
                f0 = fmaf(sv.w, fw0[c * 4 + 3], f0);
                f1 = fmaf(sv.w, fw1[c * 4 + 3], f1);
                f2 = fmaf(sv.w, fw2[c * 4 + 3], f2);
            }
            const float gsv = f0 * p0, gev = f1 * p1, gss = f2 * p2;
            accs += gss;
            av0 = fmaf(w0, gsv, fmaf(gev, u.x, av0));
            av1 = fmaf(w1, gsv, fmaf(gev, u.y, av1));
            av2 = fmaf(w2, gsv, fmaf(gev, u.z, av2));
        }
        if (s_in) {
            accs += s_in[(size_t)d * 128 + t];
            av0 += v_in[(size_t)d * 384 + t];
            av1 += v_in[(size_t)d * 384 + 128 + t];
            av2 += v_in[(size_t)d * 384 + 256 + t];
        }
        s_out[(size_t)d * 128 + t] = accs;
        v_out[(size_t)d * 384 + t] = av0;
        v_out[(size_t)d * 384 + 128 + t] = av1;
        v_out[(size_t)d * 384 + 256 + t] = av2;
    }
}

// ---------------- cat = [s, ||Vv||_axis1] ----------------
__global__ void k_catnorm(const float* __restrict__ s, const float* __restrict__ Vv,
                          float* __restrict__ cat, int n) {
    int i = blockIdx.x * blockDim.x + threadIdx.x;
    if (i >= n * F) return;
    int nn = i / F, g = i % F;
    size_t b = (size_t)nn * 384;
    float w0 = Vv[b + g], w1 = Vv[b + 128 + g], w2 = Vv[b + 256 + g];
    cat[(size_t)nn * 256 + g] = s[i];
    cat[(size_t)nn * 256 + 128 + g] = sqrtf(w0 * w0 + w1 * w1 + w2 * w2);
}

// ---------------- painn update (optionally also emit bf16 copy of v_out) ----------------
__global__ void k_update(const float* __restrict__ s_in, const float* __restrict__ v_in,
                         const float* __restrict__ a, const float* __restrict__ Uv,
                         const float* __restrict__ Vv,
                         float* __restrict__ s_out, float* __restrict__ v_out,
                         __hip_bfloat16* __restrict__ v_out_bf, int n) {
    int i = blockIdx.x * blockDim.x + threadIdx.x;
    if (i >= n * F) return;
    int nn = i / F, g = i % F;
    size_t b = (size_t)nn * 384;
    float u0 = Uv[b + g], u1 = Uv[b + 128 + g], u2 = Uv[b + 256 + g];
    float w0 = Vv[b + g], w1 = Vv[b + 128 + g], w2 = Vv[b + 256 + g];
    float inner = u0 * w0 + u1 * w1 + u2 * w2;
    float ass = a[b + g], asv = a[b + 128 + g], avv = a[b + 256 + g];
    s_out[i] = s_in[i] + ass + asv * inner;
    float r0 = v_in[b + g] + avv * u0;
    float r1 = v_in[b + 128 + g] + avv * u1;
    float r2 = v_in[b + 256 + g] + avv * u2;
    v_out[b + g] = r0;
    v_out[b + 128 + g] = r1;
    v_out[b + 256 + g] = r2;
    if (v_out_bf) {
        v_out_bf[b + g] = __float2bfloat16(r0);
        v_out_bf[b + 128 + g] = __float2bfloat16(r1);
        v_out_bf[b + 256 + g] = __float2bfloat16(r2);
    }
}

// ---------------- gated blend ----------------
__global__ void k_blend(const float* __restrict__ gate, const float* __restrict__ ms,
                        const float* __restrict__ mv, float* __restrict__ ps,
                        float* __restrict__ pv, int n) {
    int i = blockIdx.x * blockDim.x + threadIdx.x;
    if (i >= n * F) return;
    int p = i / F, g = i % F;
    float gs = gate[(size_t)p * 256 + g];
    float gv = gate[(size_t)p * 256 + 128 + g];
    ps[i] = ps[i] * gs + (1.0f - gs) * ms[i];
    size_t b = (size_t)p * 384;
#pragma unroll
    for (int i3 = 0; i3 < 3; i3++) {
        size_t o = b + (size_t)i3 * 128 + g;
        pv[o] = pv[o] * gv + (1.0f - gv) * mv[o];
    }
}

extern "C" void kernel_launch(void* const* d_in, const int* in_sizes, int n_in,
                              void* d_out, int out_size, void* d_ws, size_t ws_size,
                              hipStream_t stream) {
    const float* atom_xyz  = (const float*)d_in[0];
    const float* probe_xyz = (const float*)d_in[1];
    const float* cell      = (const float*)d_in[2];
    const float* a_disp    = (const float*)d_in[3];
    const float* p_disp    = (const float*)d_in[4];
    const float* atom_embed= (const float*)d_in[5];
    const float* ai_fw = (const float*)d_in[6];
    const float* ai_fb = (const float*)d_in[7];
    const float* ai_w1 = (const float*)d_in[8];
    const float* ai_b1 = (const float*)d_in[9];
    const float* ai_w2 = (const float*)d_in[10];
    const float* ai_b2 = (const float*)d_in[11];
    const float* au_U  = (const float*)d_in[12];
    const float* au_V  = (const float*)d_in[13];
    const float* au_w1 = (const float*)d_in[14];
    const float* au_b1 = (const float*)d_in[15];
    const float* au_w2 = (const float*)d_in[16];
    const float* au_b2 = (const float*)d_in[17];
    const float* pm_fw = (const float*)d_in[18];
    const float* pm_fb = (const float*)d_in[19];
    const float* pm_w1 = (const float*)d_in[20];
    const float* pm_b1 = (const float*)d_in[21];
    const float* pm_w2 = (const float*)d_in[22];
    const float* pm_b2 = (const float*)d_in[23];
    const float* pm_gw1= (const float*)d_in[24];
    const float* pm_gb1= (const float*)d_in[25];
    const float* pm_gw2= (const float*)d_in[26];
    const float* pm_gb2= (const float*)d_in[27];
    const float* pu_U  = (const float*)d_in[28];
    const float* pu_V  = (const float*)d_in[29];
    const float* pu_w1 = (const float*)d_in[30];
    const float* pu_b1 = (const float*)d_in[31];
    const float* pu_w2 = (const float*)d_in[32];
    const float* pu_b2 = (const float*)d_in[33];
    const int* nodes_Z = (const int*)d_in[34];
    const int* a_edges = (const int*)d_in[35];
    const int* p_edges = (const int*)d_in[36];

    const int N  = in_sizes[34];
    const int EA = in_sizes[35] / 2;
    const int EP = in_sizes[36] / 2;
    const int P  = in_sizes[1] / 3;

    char* w = (char*)d_ws;
    size_t off = 0;
    auto alloc = [&](size_t bytes) -> void* {
        void* p = w + off;
        off = (off + bytes + 255) & ~(size_t)255;
        return p;
    };
    int* a_off  = (int*)alloc((size_t)(N + 1) * 4);
    int* a_cur  = (int*)alloc((size_t)N * 4);
    int* a_eids = (int*)alloc((size_t)EA * 4);
    int* a_srcs = (int*)alloc((size_t)EA * 4);
    int* p_off  = (int*)alloc((size_t)(P + 1) * 4);
    int* p_cur  = (int*)alloc((size_t)P * 4);
    int* p_eids = (int*)alloc((size_t)EP * 4);
    int* p_srcs = (int*)alloc((size_t)EP * 4);
    float4* a_geom = (float4*)alloc((size_t)EA * 9 * 16);
    float4* p_geom = (float4*)alloc((size_t)EP * 9 * 16);
    float* s0     = (float*)alloc((size_t)N * F * 4);
    float* v0     = (float*)alloc((size_t)N * 3 * F * 4);
    float* s_list = (float*)alloc((size_t)LAYERS * N * F * 4);
    float* v_list = (float*)alloc((size_t)LAYERS * N * 3 * F * 4);
    float* ms     = (float*)alloc((size_t)P * F * 4);
    float* mv     = (float*)alloc((size_t)P * 3 * F * 4);
    float* hbuf   = (float*)alloc((size_t)P * 2 * F * 4);
    float* Uv     = (float*)alloc((size_t)P * 3 * F * 4);
    float* Vv     = (float*)alloc((size_t)P * 3 * F * 4);
    float* cat    = (float*)alloc((size_t)P * 2 * F * 4);
    float* abuf   = (float*)alloc((size_t)P * 3 * F * 4);
    float* gatebuf= (float*)alloc((size_t)P * 2 * F * 4);
    __hip_bfloat16* phi_bf   = (__hip_bfloat16*)alloc((size_t)N * 3 * F * 2);
    __hip_bfloat16* v0_bf    = (__hip_bfloat16*)alloc((size_t)N * 3 * F * 2);
    __hip_bfloat16* v_list_bf= (__hip_bfloat16*)alloc((size_t)LAYERS * N * 3 * F * 2);
    (void)ws_size; (void)n_in;

    // CSR atoms (cutoff-filtered)
    hipMemsetAsync(a_cur, 0, (size_t)N * 4, stream);
    k_count<<<(EA + 255) / 256, 256, 0, stream>>>(a_edges, atom_xyz, atom_xyz, a_disp, cell, a_cur, EA);
    k_scan<<<1, 1024, 0, stream>>>(a_cur, a_off, N);
    hipMemcpyAsync(a_cur, a_off, (size_t)N * 4, hipMemcpyDeviceToDevice, stream);
    k_scatter<<<(EA + 255) / 256, 256, 0, stream>>>(a_edges, atom_xyz, atom_xyz, a_disp, cell, a_cur, a_eids, EA);
    // CSR probes
    hipMemsetAsync(p_cur, 0, (size_t)P * 4, stream);
    k_count<<<(EP + 255) / 256, 256, 0, stream>>>(p_edges, atom_xyz, probe_xyz, p_disp, cell, p_cur, EP);
    k_scan<<<1, 1024, 0, stream>>>(p_cur, p_off, P);
    hipMemcpyAsync(p_cur, p_off, (size_t)P * 4, hipMemcpyDeviceToDevice, stream);
    k_scatter<<<(EP + 255) / 256, 256, 0, stream>>>(p_edges, atom_xyz, probe_xyz, p_disp, cell, p_cur, p_eids, EP);

    // CSR-ordered geometry
    k_geom<<<(EA + 255) / 256, 256, 0, stream>>>(atom_xyz, atom_xyz, a_disp, cell, a_edges,
                                                 a_eids, a_off, N, a_geom, a_srcs);
    k_geom<<<(EP + 255) / 256, 256, 0, stream>>>(atom_xyz, probe_xyz, p_disp, cell, p_edges,
                                                 p_eids, p_off, P, p_geom, p_srcs);

    // init node states
    k_embed<<<(N * F + 255) / 256, 256, 0, stream>>>(nodes_Z, atom_embed, s0, N);
    hipMemsetAsync(v0, 0, (size_t)N * 3 * F * 4, stream);
    hipMemsetAsync(v0_bf, 0, (size_t)N * 3 * F * 2, stream);

    auto gemm = [&](const float* A, const float* B, const float* bias, void* C,
                    int M, int Nc, int K, int act, int outmode = 0) {
        dim3 g(Nc / 64, (M + 63) / 64);
        k_gemm<<<g, 256, 0, stream>>>(A, B, bias, C, M, Nc, K, act, outmode);
    };

    // ---- atom message-passing layers ----
    for (int l = 0; l < LAYERS; l++) {
        const float* scur = l ? (s_list + (size_t)(l - 1) * N * F) : s0;
        const float* vcur = l ? (v_list + (size_t)(l - 1) * N * 3 * F) : v0;
        const __hip_bfloat16* vcur_bf = l ? (v_list_bf + (size_t)(l - 1) * N * 3 * F) : v0_bf;
        gemm(scur, ai_w1 + (size_t)l * F * F, ai_b1 + (size_t)l * F, hbuf, N, F, F, 1);
        gemm(hbuf, ai_w2 + (size_t)l * F * 3 * F, ai_b2 + (size_t)l * 3 * F, phi_bf, N, 3 * F, F, 0, 1);
        k_gather<<<(N + 1) / 2, 256, 0, stream>>>(a_geom, a_srcs, a_off, phi_bf, vcur_bf,
                                        ai_fw + (size_t)l * KB * 3 * F, ai_fb + (size_t)l * 3 * F,
                                        scur, vcur, ms, mv, N);
        gemm(mv, au_U + (size_t)l * F * F, nullptr, Uv, 3 * N, F, F, 0);
        gemm(mv, au_V + (size_t)l * F * F, nullptr, Vv, 3 * N, F, F, 0);
        k_catnorm<<<(N * F + 255) / 256, 256, 0, stream>>>(ms, Vv, cat, N);
        gemm(cat, au_w1 + (size_t)l * 2 * F * F, au_b1 + (size_t)l * F, hbuf, N, F, 2 * F, 1);
        gemm(hbuf, au_w2 + (size_t)l * F * 3 * F, au_b2 + (size_t)l * 3 * F, abuf, N, 3 * F, F, 0);
        k_update<<<(N * F + 255) / 256, 256, 0, stream>>>(ms, mv, abuf, Uv, Vv,
                  s_list + (size_t)l * N * F, v_list + (size_t)l * N * 3 * F,
                  v_list_bf + (size_t)l * N * 3 * F, N);
    }

    // ---- probe phase ----
    float* ps = (float*)d_out;
    float* pv = (float*)d_out + (size_t)P * F;
    hipMemsetAsync(d_out, 0, (size_t)out_size * 4, stream);

    for (int l = 0; l < LAYERS; l++) {
        const float* sl = s_list + (size_t)l * N * F;
        const __hip_bfloat16* vl_bf = v_list_bf + (size_t)l * N * 3 * F;
        gemm(sl, pm_w1 + (size_t)l * F * F, pm_b1 + (size_t)l * F, hbuf, N, F, F, 1);
        gemm(hbuf, pm_w2 + (size_t)l * F * 3 * F, pm_b2 + (size_t)l * 3 * F, phi_bf, N, 3 * F, F, 0, 1);
        k_gather<<<(P + 1) / 2, 256, 0, stream>>>(p_geom, p_srcs, p_off, phi_bf, vl_bf,
                                        pm_fw + (size_t)l * KB * 3 * F, pm_fb + (size_t)l * 3 * F,
                                        nullptr, nullptr, ms, mv, P);
        gemm(ms, pm_gw1 + (size_t)l * F * 2 * F, pm_gb1 + (size_t)l * 2 * F, hbuf, P, 2 * F, F, 1);
        gemm(hbuf, pm_gw2 + (size_t)l * 2 * F * 2 * F, pm_gb2 + (size_t)l * 2 * F, gatebuf, P, 2 * F, 2 * F, 2);
        k_blend<<<(P * F + 255) / 256, 256, 0, stream>>>(gatebuf, ms, mv, ps, pv, P);
        gemm(pv, pu_U + (size_t)l * F * F, nullptr, Uv, 3 * P, F, F, 0);
        gemm(pv, pu_V + (size_t)l * F * F, nullptr, Vv, 3 * P, F, F, 0);
        k_catnorm<<<(P * F + 255) / 256, 256, 0, stream>>>(ps, Vv, cat, P);
        gemm(cat, pu_w1 + (size_t)l * 2 * F * F, pu_b1 + (size_t)l * F, hbuf, P, F, 2 * F, 1);
        gemm(hbuf, pu_w2 + (size_t)l * F * 3 * F, pu_b2 + (size_t)l * 3 * F, abuf, P, 3 * F, F, 0);
        k_update<<<(P * F + 255) / 256, 256, 0, stream>>>(ps, pv, abuf, Uv, Vv, ps, pv, nullptr, P);
    }
}

// Round 4
// 1222.825 us; speedup vs baseline: 1.1659x; 1.1356x over previous
//
#include <hip/hip_runtime.h>
#include <hip/hip_bf16.h>
#include <math.h>

#define PI_F 3.14159265358979323846f

static constexpr int F = 128;
static constexpr int KB = 30;      // sinc basis size
static constexpr int LAYERS = 3;
static constexpr float CUT = 4.0f;
static constexpr int BINS = 1024;  // table bins; rows = BINS+1
static constexpr int TROW = 512;   // packed table row stride (floats): 128 lanes * 4 slots

__device__ __forceinline__ float bf2f(unsigned short u) {
    union { unsigned int i; float f; } c; c.i = ((unsigned int)u) << 16; return c.f;
}

__device__ __forceinline__ float edge_dist(const float* __restrict__ sxyz,
                                           const float* __restrict__ dxyz,
                                           const float* __restrict__ disp,
                                           const float* __restrict__ cell,
                                           int s, int d, int e, float* dx) {
    const float* dp = disp + 3 * (size_t)e;
#pragma unroll
    for (int i = 0; i < 3; i++) {
        float dc = dp[0] * cell[0 * 3 + i] + dp[1] * cell[1 * 3 + i] + dp[2] * cell[2 * 3 + i];
        dx[i] = dxyz[3 * d + i] - (sxyz[3 * s + i] + dc);
    }
    return sqrtf(dx[0] * dx[0] + dx[1] * dx[1] + dx[2] * dx[2]);
}

// ---------------- CSR build (cutoff-filtered) ----------------
__global__ void k_count(const int* __restrict__ edges, const float* __restrict__ sxyz,
                        const float* __restrict__ dxyz, const float* __restrict__ disp,
                        const float* __restrict__ cell, int* __restrict__ cnt, int E) {
    int i = blockIdx.x * blockDim.x + threadIdx.x;
    if (i >= E) return;
    int s = edges[2 * i], d = edges[2 * i + 1];
    float dx[3];
    float dist = edge_dist(sxyz, dxyz, disp, cell, s, d, i, dx);
    if (dist < CUT) atomicAdd(&cnt[d], 1);
}

__global__ void k_scan(const int* __restrict__ cnt, int* __restrict__ off, int n) {
    __shared__ int part[1024];
    int t = threadIdx.x;
    int chunk = (n + 1023) / 1024;
    int b = t * chunk; if (b > n) b = n;
    int e = b + chunk; if (e > n) e = n;
    int s = 0;
    for (int i = b; i < e; i++) s += cnt[i];
    part[t] = s;
    __syncthreads();
    for (int o = 1; o < 1024; o <<= 1) {
        int v = part[t];
        int add = (t >= o) ? part[t - o] : 0;
        __syncthreads();
        part[t] = v + add;
        __syncthreads();
    }
    int run = (t == 0) ? 0 : part[t - 1];
    for (int i = b; i < e; i++) { off[i] = run; run += cnt[i]; }
    if (t == 1023) off[n] = part[1023];
}

__global__ void k_scatter(const int* __restrict__ edges, const float* __restrict__ sxyz,
                          const float* __restrict__ dxyz, const float* __restrict__ disp,
                          const float* __restrict__ cell, int* __restrict__ cur,
                          int* __restrict__ eids, int E) {
    int i = blockIdx.x * blockDim.x + threadIdx.x;
    if (i >= E) return;
    int s = edges[2 * i], d = edges[2 * i + 1];
    float dx[3];
    float dist = edge_dist(sxyz, dxyz, disp, cell, s, d, i, dx);
    if (dist < CUT) {
        int pos = atomicAdd(&cur[d], 1);
        eids[pos] = i;
    }
}

// ---------------- edge records, CSR-ordered: float4(u0,u1,u2, dist*BINS/CUT) ----------------
__global__ void k_geom_rec(const float* __restrict__ sxyz, const float* __restrict__ dxyz,
                           const float* __restrict__ disp, const float* __restrict__ cell,
                           const int* __restrict__ edges, const int* __restrict__ eids,
                           const int* __restrict__ eoff, int ndst,
                           float4* __restrict__ erec, int* __restrict__ srcs) {
    int pos = blockIdx.x * blockDim.x + threadIdx.x;
    if (pos >= eoff[ndst]) return;
    int e = eids[pos];
    int s = edges[2 * e], d = edges[2 * e + 1];
    float dx[3];
    float dist = edge_dist(sxyz, dxyz, disp, cell, s, d, e, dx);
    float inv = 1.0f / fmaxf(dist, 1e-12f);
    float db = fminf(dist * ((float)BINS / CUT), (float)BINS - 0.0001f);
    erec[pos] = make_float4(dx[0] * inv, dx[1] * inv, dx[2] * inv, db);
    srcs[pos] = s;
}

// ---------------- S' basis: S'(i,k) = cc_i * st_k(d_i), S'(i,30)=cc_i, S'(i,31)=0 ----------------
__global__ void k_sbuild(float* __restrict__ Sp) {
    int i = blockIdx.x * blockDim.x + threadIdx.x;
    if (i > BINS) return;
    float d = (float)i * (CUT / (float)BINS);
    float cc = (d < CUT) ? 0.5f * (cosf(PI_F * d / CUT) + 1.0f) : 0.0f;
    float* row = Sp + (size_t)i * 32;
#pragma unroll
    for (int k = 0; k < KB; k++) {
        float kk = (float)(k + 1);
        float st = (d > 1e-12f) ? sinf(PI_F * d * kk / CUT) / d : PI_F * kk / CUT;
        row[k] = cc * st;
    }
    row[30] = cc;
    row[31] = 0.f;
}

// ---------------- assemble fw' (6 tables x 32 x 384) ----------------
__global__ void k_fwpack(const float* __restrict__ ai_fw, const float* __restrict__ ai_fb,
                         const float* __restrict__ pm_fw, const float* __restrict__ pm_fb,
                         float* __restrict__ fwp) {
    int i = blockIdx.x * blockDim.x + threadIdx.x;
    if (i >= 6 * 32 * 384) return;
    int tbl = i / (32 * 384);
    int k = (i / 384) % 32;
    int c = i % 384;
    const float* fw = (tbl < 3) ? ai_fw + (size_t)tbl * KB * 384 : pm_fw + (size_t)(tbl - 3) * KB * 384;
    const float* fb = (tbl < 3) ? ai_fb + (size_t)tbl * 384 : pm_fb + (size_t)(tbl - 3) * 384;
    float v = 0.f;
    if (k < KB) v = fw[(size_t)k * 384 + c];
    else if (k == 30) v = fb[c];
    fwp[i] = v;
}

// ---------------- init: s0 = embed[Z] ----------------
__global__ void k_embed(const int* __restrict__ Z, const float* __restrict__ emb,
                        float* __restrict__ s, int n) {
    int i = blockIdx.x * blockDim.x + threadIdx.x;
    if (i < n * F) s[i] = emb[(size_t)Z[i / F] * F + (i % F)];
}

// ---------------- generic f32 GEMM: C = act(A@B + bias) ----------------
// act: 0 none, 1 silu, 2 sigmoid.
// outmode: 0 f32 flat, 1 bf16 flat, 2 bf16 packed384 ([m][128][4], slot=(c>>7)), 3 f32 packed384.
__global__ __launch_bounds__(256) void k_gemm(const float* __restrict__ A, const float* __restrict__ B,
                                              const float* __restrict__ bias, void* __restrict__ Cout,
                                              int M, int N, int K, int act, int outmode) {
    __shared__ float As[16][64];
    __shared__ float Bs[16][64];
    int tid = threadIdx.x;
    int bm = blockIdx.y * 64, bn = blockIdx.x * 64;
    int tx = tid & 15, ty = tid >> 4;
    float acc[4][4] = {};
    int arow = tid >> 2;
    int acol = (tid & 3) * 4;
    int brow = tid >> 4;
    int bcol = (tid & 15) * 4;
    for (int k0 = 0; k0 < K; k0 += 16) {
        float4 av = make_float4(0.f, 0.f, 0.f, 0.f);
        int gm = bm + arow;
        if (gm < M) av = *reinterpret_cast<const float4*>(A + (size_t)gm * K + k0 + acol);
        As[acol + 0][arow] = av.x; As[acol + 1][arow] = av.y;
        As[acol + 2][arow] = av.z; As[acol + 3][arow] = av.w;
        float4 bv = *reinterpret_cast<const float4*>(B + (size_t)(k0 + brow) * N + bn + bcol);
        Bs[brow][bcol + 0] = bv.x; Bs[brow][bcol + 1] = bv.y;
        Bs[brow][bcol + 2] = bv.z; Bs[brow][bcol + 3] = bv.w;
        __syncthreads();
#pragma unroll
        for (int k = 0; k < 16; k++) {
            float a0 = As[k][ty * 4 + 0], a1 = As[k][ty * 4 + 1];
            float a2 = As[k][ty * 4 + 2], a3 = As[k][ty * 4 + 3];
            float b0 = Bs[k][tx * 4 + 0], b1 = Bs[k][tx * 4 + 1];
            float b2 = Bs[k][tx * 4 + 2], b3 = Bs[k][tx * 4 + 3];
            acc[0][0] += a0 * b0; acc[0][1] += a0 * b1; acc[0][2] += a0 * b2; acc[0][3] += a0 * b3;
            acc[1][0] += a1 * b0; acc[1][1] += a1 * b1; acc[1][2] += a1 * b2; acc[1][3] += a1 * b3;
            acc[2][0] += a2 * b0; acc[2][1] += a2 * b1; acc[2][2] += a2 * b2; acc[2][3] += a2 * b3;
            acc[3][0] += a3 * b0; acc[3][1] += a3 * b1; acc[3][2] += a3 * b2; acc[3][3] += a3 * b3;
        }
        __syncthreads();
    }
#pragma unroll
    for (int i = 0; i < 4; i++) {
        int gm = bm + ty * 4 + i;
        if (gm >= M) continue;
#pragma unroll
        for (int j = 0; j < 4; j++) {
            int gn = bn + tx * 4 + j;
            float v = acc[i][j];
            if (bias) v += bias[gn];
            if (act == 1) v = v / (1.0f + expf(-v));
            else if (act == 2) v = 1.0f / (1.0f + expf(-v));
            if (outmode == 0) ((float*)Cout)[(size_t)gm * N + gn] = v;
            else if (outmode == 1) ((__hip_bfloat16*)Cout)[(size_t)gm * N + gn] = __float2bfloat16(v);
            else if (outmode == 2) ((__hip_bfloat16*)Cout)[(size_t)gm * 512 + (gn & 127) * 4 + (gn >> 7)] = __float2bfloat16(v);
            else ((float*)Cout)[(size_t)gm * 512 + (gn & 127) * 4 + (gn >> 7)] = v;
        }
    }
}

// ---------------- fused edge messages + segment sum (table-driven) ----------------
__global__ __launch_bounds__(256) void k_gather(
    const float4* __restrict__ erec, const int* __restrict__ srcs,
    const int* __restrict__ eoff, const float* __restrict__ T,
    const __hip_bfloat16* __restrict__ phi, const __hip_bfloat16* __restrict__ vsend,
    const float* __restrict__ s_in, const float* __restrict__ v_in,
    float* __restrict__ s_out, float* __restrict__ v_out, int ndst) {
    const int t = threadIdx.x & 127;     // column owner: t, t+128, t+256
    const int half = threadIdx.x >> 7;   // 2 destinations per block
    const float4* __restrict__ T4 = reinterpret_cast<const float4*>(T);

    for (int d = blockIdx.x * 2 + half; d < ndst; d += gridDim.x * 2) {
        const int e0 = eoff[d], e1 = eoff[d + 1];
        float accs = 0.f, av0 = 0.f, av1 = 0.f, av2 = 0.f;

        auto body = [&](int ii) {
            const int src = srcs[ii];
            const float4 u = erec[ii];
            const int bin = (int)u.w;
            const float fr = u.w - (float)bin;
            const float4 ta = T4[(size_t)bin * 128 + t];
            const float4 tb = T4[(size_t)(bin + 1) * 128 + t];
            const ushort4 ph = *reinterpret_cast<const ushort4*>(phi + (size_t)src * 512 + t * 4);
            const ushort4 vs = *reinterpret_cast<const ushort4*>(vsend + (size_t)src * 512 + t * 4);
            const float f0 = fmaf(fr, tb.x - ta.x, ta.x);
            const float f1 = fmaf(fr, tb.y - ta.y, ta.y);
            const float f2 = fmaf(fr, tb.z - ta.z, ta.z);
            const float gsv = f0 * bf2f(ph.x);
            const float gev = f1 * bf2f(ph.y);
            const float gss = f2 * bf2f(ph.z);
            accs += gss;
            av0 = fmaf(bf2f(vs.x), gsv, fmaf(gev, u.x, av0));
            av1 = fmaf(bf2f(vs.y), gsv, fmaf(gev, u.y, av1));
            av2 = fmaf(bf2f(vs.z), gsv, fmaf(gev, u.z, av2));
        };

        int ii = e0;
        for (; ii + 1 < e1; ii += 2) { body(ii); body(ii + 1); }
        if (ii < e1) body(ii);

        if (s_in) {
            accs += s_in[(size_t)d * 128 + t];
            av0 += v_in[(size_t)d * 384 + t];
            av1 += v_in[(size_t)d * 384 + 128 + t];
            av2 += v_in[(size_t)d * 384 + 256 + t];
        }
        s_out[(size_t)d * 128 + t] = accs;
        v_out[(size_t)d * 384 + t] = av0;
        v_out[(size_t)d * 384 + 128 + t] = av1;
        v_out[(size_t)d * 384 + 256 + t] = av2;
    }
}

// ---------------- cat = [s, ||Vv||_axis1] ----------------
__global__ void k_catnorm(const float* __restrict__ s, const float* __restrict__ Vv,
                          float* __restrict__ cat, int n) {
    int i = blockIdx.x * blockDim.x + threadIdx.x;
    if (i >= n * F) return;
    int nn = i / F, g = i % F;
    size_t b = (size_t)nn * 384;
    float w0 = Vv[b + g], w1 = Vv[b + 128 + g], w2 = Vv[b + 256 + g];
    cat[(size_t)nn * 256 + g] = s[i];
    cat[(size_t)nn * 256 + 128 + g] = sqrtf(w0 * w0 + w1 * w1 + w2 * w2);
}

// ---------------- painn update (optionally emit packed-bf16 copy of v_out) ----------------
__global__ void k_update(const float* __restrict__ s_in, const float* __restrict__ v_in,
                         const float* __restrict__ a, const float* __restrict__ Uv,
                         const float* __restrict__ Vv,
                         float* __restrict__ s_out, float* __restrict__ v_out,
                         __hip_bfloat16* __restrict__ v_out_bf, int n) {
    int i = blockIdx.x * blockDim.x + threadIdx.x;
    if (i >= n * F) return;
    int nn = i / F, g = i % F;
    size_t b = (size_t)nn * 384;
    float u0 = Uv[b + g], u1 = Uv[b + 128 + g], u2 = Uv[b + 256 + g];
    float w0 = Vv[b + g], w1 = Vv[b + 128 + g], w2 = Vv[b + 256 + g];
    float inner = u0 * w0 + u1 * w1 + u2 * w2;
    float ass = a[b + g], asv = a[b + 128 + g], avv = a[b + 256 + g];
    s_out[i] = s_in[i] + ass + asv * inner;
    float r0 = v_in[b + g] + avv * u0;
    float r1 = v_in[b + 128 + g] + avv * u1;
    float r2 = v_in[b + 256 + g] + avv * u2;
    v_out[b + g] = r0;
    v_out[b + 128 + g] = r1;
    v_out[b + 256 + g] = r2;
    if (v_out_bf) {
        size_t pb = (size_t)nn * 512 + (size_t)g * 4;
        v_out_bf[pb + 0] = __float2bfloat16(r0);
        v_out_bf[pb + 1] = __float2bfloat16(r1);
        v_out_bf[pb + 2] = __float2bfloat16(r2);
    }
}

// ---------------- gated blend ----------------
__global__ void k_blend(const float* __restrict__ gate, const float* __restrict__ ms,
                        const float* __restrict__ mv, float* __restrict__ ps,
                        float* __restrict__ pv, int n) {
    int i = blockIdx.x * blockDim.x + threadIdx.x;
    if (i >= n * F) return;
    int p = i / F, g = i % F;
    float gs = gate[(size_t)p * 256 + g];
    float gv = gate[(size_t)p * 256 + 128 + g];
    ps[i] = ps[i] * gs + (1.0f - gs) * ms[i];
    size_t b = (size_t)p * 384;
#pragma unroll
    for (int i3 = 0; i3 < 3; i3++) {
        size_t o = b + (size_t)i3 * 128 + g;
        pv[o] = pv[o] * gv + (1.0f - gv) * mv[o];
    }
}

extern "C" void kernel_launch(void* const* d_in, const int* in_sizes, int n_in,
                              void* d_out, int out_size, void* d_ws, size_t ws_size,
                              hipStream_t stream) {
    const float* atom_xyz  = (const float*)d_in[0];
    const float* probe_xyz = (const float*)d_in[1];
    const float* cell      = (const float*)d_in[2];
    const float* a_disp    = (const float*)d_in[3];
    const float* p_disp    = (const float*)d_in[4];
    const float* atom_embed= (const float*)d_in[5];
    const float* ai_fw = (const float*)d_in[6];
    const float* ai_fb = (const float*)d_in[7];
    const float* ai_w1 = (const float*)d_in[8];
    const float* ai_b1 = (const float*)d_in[9];
    const float* ai_w2 = (const float*)d_in[10];
    const float* ai_b2 = (const float*)d_in[11];
    const float* au_U  = (const float*)d_in[12];
    const float* au_V  = (const float*)d_in[13];
    const float* au_w1 = (const float*)d_in[14];
    const float* au_b1 = (const float*)d_in[15];
    const float* au_w2 = (const float*)d_in[16];
    const float* au_b2 = (const float*)d_in[17];
    const float* pm_fw = (const float*)d_in[18];
    const float* pm_fb = (const float*)d_in[19];
    const float* pm_w1 = (const float*)d_in[20];
    const float* pm_b1 = (const float*)d_in[21];
    const float* pm_w2 = (const float*)d_in[22];
    const float* pm_b2 = (const float*)d_in[23];
    const float* pm_gw1= (const float*)d_in[24];
    const float* pm_gb1= (const float*)d_in[25];
    const float* pm_gw2= (const float*)d_in[26];
    const float* pm_gb2= (const float*)d_in[27];
    const float* pu_U  = (const float*)d_in[28];
    const float* pu_V  = (const float*)d_in[29];
    const float* pu_w1 = (const float*)d_in[30];
    const float* pu_b1 = (const float*)d_in[31];
    const float* pu_w2 = (const float*)d_in[32];
    const float* pu_b2 = (const float*)d_in[33];
    const int* nodes_Z = (const int*)d_in[34];
    const int* a_edges = (const int*)d_in[35];
    const int* p_edges = (const int*)d_in[36];

    const int N  = in_sizes[34];
    const int EA = in_sizes[35] / 2;
    const int EP = in_sizes[36] / 2;
    const int P  = in_sizes[1] / 3;

    char* w = (char*)d_ws;
    size_t off = 0;
    auto alloc = [&](size_t bytes) -> void* {
        void* p = w + off;
        off = (off + bytes + 255) & ~(size_t)255;
        return p;
    };
    int* a_off  = (int*)alloc((size_t)(N + 1) * 4);
    int* a_cur  = (int*)alloc((size_t)N * 4);
    int* a_eids = (int*)alloc((size_t)EA * 4);
    int* a_srcs = (int*)alloc((size_t)EA * 4);
    int* p_off  = (int*)alloc((size_t)(P + 1) * 4);
    int* p_cur  = (int*)alloc((size_t)P * 4);
    int* p_eids = (int*)alloc((size_t)EP * 4);
    int* p_srcs = (int*)alloc((size_t)EP * 4);
    float4* a_erec = (float4*)alloc((size_t)EA * 16);
    float4* p_erec = (float4*)alloc((size_t)EP * 16);
    float* Sp   = (float*)alloc((size_t)(BINS + 1) * 32 * 4);
    float* fwp  = (float*)alloc((size_t)6 * 32 * 384 * 4);
    float* Tpack= (float*)alloc((size_t)6 * (BINS + 1) * TROW * 4);
    float* s0     = (float*)alloc((size_t)N * F * 4);
    float* v0     = (float*)alloc((size_t)N * 3 * F * 4);
    float* s_list = (float*)alloc((size_t)LAYERS * N * F * 4);
    float* v_list = (float*)alloc((size_t)LAYERS * N * 3 * F * 4);
    float* ms     = (float*)alloc((size_t)P * F * 4);
    float* mv     = (float*)alloc((size_t)P * 3 * F * 4);
    float* hbuf   = (float*)alloc((size_t)P * 2 * F * 4);
    float* Uv     = (float*)alloc((size_t)P * 3 * F * 4);
    float* Vv     = (float*)alloc((size_t)P * 3 * F * 4);
    float* cat    = (float*)alloc((size_t)P * 2 * F * 4);
    float* abuf   = (float*)alloc((size_t)P * 3 * F * 4);
    float* gatebuf= (float*)alloc((size_t)P * 2 * F * 4);
    __hip_bfloat16* phi_bf   = (__hip_bfloat16*)alloc((size_t)N * 512 * 2);
    __hip_bfloat16* v0_bf    = (__hip_bfloat16*)alloc((size_t)N * 512 * 2);
    __hip_bfloat16* v_list_bf= (__hip_bfloat16*)alloc((size_t)LAYERS * N * 512 * 2);
    (void)ws_size; (void)n_in;

    // CSR atoms (cutoff-filtered)
    hipMemsetAsync(a_cur, 0, (size_t)N * 4, stream);
    k_count<<<(EA + 255) / 256, 256, 0, stream>>>(a_edges, atom_xyz, atom_xyz, a_disp, cell, a_cur, EA);
    k_scan<<<1, 1024, 0, stream>>>(a_cur, a_off, N);
    hipMemcpyAsync(a_cur, a_off, (size_t)N * 4, hipMemcpyDeviceToDevice, stream);
    k_scatter<<<(EA + 255) / 256, 256, 0, stream>>>(a_edges, atom_xyz, atom_xyz, a_disp, cell, a_cur, a_eids, EA);
    // CSR probes
    hipMemsetAsync(p_cur, 0, (size_t)P * 4, stream);
    k_count<<<(EP + 255) / 256, 256, 0, stream>>>(p_edges, atom_xyz, probe_xyz, p_disp, cell, p_cur, EP);
    k_scan<<<1, 1024, 0, stream>>>(p_cur, p_off, P);
    hipMemcpyAsync(p_cur, p_off, (size_t)P * 4, hipMemcpyDeviceToDevice, stream);
    k_scatter<<<(EP + 255) / 256, 256, 0, stream>>>(p_edges, atom_xyz, probe_xyz, p_disp, cell, p_cur, p_eids, EP);

    // edge records (CSR-ordered)
    k_geom_rec<<<(EA + 255) / 256, 256, 0, stream>>>(atom_xyz, atom_xyz, a_disp, cell, a_edges,
                                                     a_eids, a_off, N, a_erec, a_srcs);
    k_geom_rec<<<(EP + 255) / 256, 256, 0, stream>>>(atom_xyz, probe_xyz, p_disp, cell, p_edges,
                                                     p_eids, p_off, P, p_erec, p_srcs);

    // filter tables: T_tbl = S' @ fw'_tbl (cc and fb folded), packed f32 [bin][128][4]
    k_sbuild<<<(BINS + 256) / 256, 256, 0, stream>>>(Sp);
    k_fwpack<<<(6 * 32 * 384 + 255) / 256, 256, 0, stream>>>(ai_fw, ai_fb, pm_fw, pm_fb, fwp);
    for (int tbl = 0; tbl < 6; tbl++) {
        dim3 g(384 / 64, (BINS + 1 + 63) / 64);
        k_gemm<<<g, 256, 0, stream>>>(Sp, fwp + (size_t)tbl * 32 * 384, nullptr,
                                      Tpack + (size_t)tbl * (BINS + 1) * TROW,
                                      BINS + 1, 384, 32, 0, 3);
    }

    // init node states
    k_embed<<<(N * F + 255) / 256, 256, 0, stream>>>(nodes_Z, atom_embed, s0, N);
    hipMemsetAsync(v0, 0, (size_t)N * 3 * F * 4, stream);
    hipMemsetAsync(v0_bf, 0, (size_t)N * 512 * 2, stream);

    auto gemm = [&](const float* A, const float* B, const float* bias, void* C,
                    int M, int Nc, int K, int act, int outmode = 0) {
        dim3 g(Nc / 64, (M + 63) / 64);
        k_gemm<<<g, 256, 0, stream>>>(A, B, bias, C, M, Nc, K, act, outmode);
    };

    // ---- atom message-passing layers ----
    for (int l = 0; l < LAYERS; l++) {
        const float* scur = l ? (s_list + (size_t)(l - 1) * N * F) : s0;
        const float* vcur = l ? (v_list + (size_t)(l - 1) * N * 3 * F) : v0;
        const __hip_bfloat16* vcur_bf = l ? (v_list_bf + (size_t)(l - 1) * N * 512) : v0_bf;
        gemm(scur, ai_w1 + (size_t)l * F * F, ai_b1 + (size_t)l * F, hbuf, N, F, F, 1);
        gemm(hbuf, ai_w2 + (size_t)l * F * 3 * F, ai_b2 + (size_t)l * 3 * F, phi_bf, N, 3 * F, F, 0, 2);
        k_gather<<<(N + 1) / 2, 256, 0, stream>>>(a_erec, a_srcs, a_off,
                                        Tpack + (size_t)l * (BINS + 1) * TROW,
                                        phi_bf, vcur_bf, scur, vcur, ms, mv, N);
        gemm(mv, au_U + (size_t)l * F * F, nullptr, Uv, 3 * N, F, F, 0);
        gemm(mv, au_V + (size_t)l * F * F, nullptr, Vv, 3 * N, F, F, 0);
        k_catnorm<<<(N * F + 255) / 256, 256, 0, stream>>>(ms, Vv, cat, N);
        gemm(cat, au_w1 + (size_t)l * 2 * F * F, au_b1 + (size_t)l * F, hbuf, N, F, 2 * F, 1);
        gemm(hbuf, au_w2 + (size_t)l * F * 3 * F, au_b2 + (size_t)l * 3 * F, abuf, N, 3 * F, F, 0);
        k_update<<<(N * F + 255) / 256, 256, 0, stream>>>(ms, mv, abuf, Uv, Vv,
                  s_list + (size_t)l * N * F, v_list + (size_t)l * N * 3 * F,
                  v_list_bf + (size_t)l * N * 512, N);
    }

    // ---- probe phase ----
    float* ps = (float*)d_out;
    float* pv = (float*)d_out + (size_t)P * F;
    hipMemsetAsync(d_out, 0, (size_t)out_size * 4, stream);

    for (int l = 0; l < LAYERS; l++) {
        const float* sl = s_list + (size_t)l * N * F;
        const __hip_bfloat16* vl_bf = v_list_bf + (size_t)l * N * 512;
        gemm(sl, pm_w1 + (size_t)l * F * F, pm_b1 + (size_t)l * F, hbuf, N, F, F, 1);
        gemm(hbuf, pm_w2 + (size_t)l * F * 3 * F, pm_b2 + (size_t)l * 3 * F, phi_bf, N, 3 * F, F, 0, 2);
        k_gather<<<(P + 1) / 2, 256, 0, stream>>>(p_erec, p_srcs, p_off,
                                        Tpack + (size_t)(3 + l) * (BINS + 1) * TROW,
                                        phi_bf, vl_bf, nullptr, nullptr, ms, mv, P);
        gemm(ms, pm_gw1 + (size_t)l * F * 2 * F, pm_gb1 + (size_t)l * 2 * F, hbuf, P, 2 * F, F, 1);
        gemm(hbuf, pm_gw2 + (size_t)l * 2 * F * 2 * F, pm_gb2 + (size_t)l * 2 * F, gatebuf, P, 2 * F, 2 * F, 2);
        k_blend<<<(P * F + 255) / 256, 256, 0, stream>>>(gatebuf, ms, mv, ps, pv, P);
        gemm(pv, pu_U + (size_t)l * F * F, nullptr, Uv, 3 * P, F, F, 0);
        gemm(pv, pu_V + (size_t)l * F * F, nullptr, Vv, 3 * P, F, F, 0);
        k_catnorm<<<(P * F + 255) / 256, 256, 0, stream>>>(ps, Vv, cat, P);
        gemm(cat, pu_w1 + (size_t)l * 2 * F * F, pu_b1 + (size_t)l * F, hbuf, P, F, 2 * F, 1);
        gemm(hbuf, pu_w2 + (size_t)l * F * 3 * F, pu_b2 + (size_t)l * 3 * F, abuf, P, 3 * F, F, 0);
        k_update<<<(P * F + 255) / 256, 256, 0, stream>>>(ps, pv, abuf, Uv, Vv, ps, pv, nullptr, P);
    }
}